// Round 2
// baseline (8502.364 us; speedup 1.0000x reference)
//
#include <hip/hip_runtime.h>
#include <hip/hip_cooperative_groups.h>

namespace cg = cooperative_groups;

typedef float f32x4 __attribute__((ext_vector_type(4)));
typedef _Float16 f16x8 __attribute__((ext_vector_type(8)));

#define BDIM 256
#define GRID 256
// LDS layout (recurrence): wts 73728 B | gates 64*148*4=37888 B | misc 240*4=960 B
#define SMEM_BYTES (73728 + 37888 + 960)

struct Params {
    const float *x, *bWf, *bbf, *bWr, *bbr;
    const float *tWf, *tbf, *tWr, *tbr, *donb;
    const float *wih0, *whh0, *bih0, *bhh0;
    const float *wih1, *whh1, *bih1, *bhh1;
    const float *pW, *pb;
    float *out;
    float *brA, *brB, *trA, *trB, *seqT;
    _Float16 *h0b, *h1b;   // fp16 ping-pong state buffers, fragment-ready layout
};

__device__ __forceinline__ f16x8 cvt8(float4 a, float4 b) {
    f16x8 r;
    r[0] = (_Float16)a.x; r[1] = (_Float16)a.y; r[2] = (_Float16)a.z; r[3] = (_Float16)a.w;
    r[4] = (_Float16)b.x; r[5] = (_Float16)b.y; r[6] = (_Float16)b.z; r[7] = (_Float16)b.w;
    return r;
}

__device__ __forceinline__ unsigned short f2hbits(float x) {
    union { _Float16 h; unsigned short u; } v; v.h = (_Float16)x; return v.u;
}

__device__ __forceinline__ unsigned long long pack4(const float* v) {
    return  (unsigned long long)f2hbits(v[0])
         | ((unsigned long long)f2hbits(v[1]) << 16)
         | ((unsigned long long)f2hbits(v[2]) << 32)
         | ((unsigned long long)f2hbits(v[3]) << 48);
}

__device__ __forceinline__ float sigmoidf_(float x) { return 1.f / (1.f + __expf(-x)); }
__device__ __forceinline__ float tanhf_(float x)    { return 1.f - 2.f / (__expf(2.f * x) + 1.f); }

// Generic 64x64-tile GEMM: C[m0..+64, n0..+64] = op(A[M,K] @ W[N,K]^T + bias)
// A,W are f32 global; staged to LDS as fp16 (row-padded to 72 halfs -> 2-way banks only).
__device__ void gemm_tile(const float* __restrict__ A, int lda,
                          const float* __restrict__ W, int ldw,
                          const float* __restrict__ bias, int biasScalar,
                          int relu, float* __restrict__ C, int ldc, int transOut,
                          int K, int m0, int n0, char* smem)
{
    _Float16* At = (_Float16*)smem;            // [64][72]
    _Float16* Bt = (_Float16*)smem + 64 * 72;  // [64][72]
    const int tid = threadIdx.x;
    const int wv = tid >> 6, lane = tid & 63;
    f32x4 acc[4];
#pragma unroll
    for (int i = 0; i < 4; ++i) acc[i] = (f32x4){0.f, 0.f, 0.f, 0.f};

    const int srow = tid >> 2, sc0 = (tid & 3) * 16;
    for (int kc = 0; kc < K; kc += 64) {
        const float* asrc = A + (size_t)(m0 + srow) * lda + kc + sc0;
        const float* wsrc = W + (size_t)(n0 + srow) * ldw + kc + sc0;
#pragma unroll
        for (int h = 0; h < 2; ++h) {
            float4 v0 = make_float4(0, 0, 0, 0), v1 = v0, u0 = v0, u1 = v0;
            if (kc + sc0 + h * 8 < K) {        // K % 8 == 0 for all our shapes
                v0 = *(const float4*)(asrc + h * 8);
                v1 = *(const float4*)(asrc + h * 8 + 4);
                u0 = *(const float4*)(wsrc + h * 8);
                u1 = *(const float4*)(wsrc + h * 8 + 4);
            }
            *(f16x8*)&At[srow * 72 + sc0 + h * 8] = cvt8(v0, v1);
            *(f16x8*)&Bt[srow * 72 + sc0 + h * 8] = cvt8(u0, u1);
        }
        __syncthreads();
#pragma unroll
        for (int k2 = 0; k2 < 2; ++k2) {
            f16x8 a = *(const f16x8*)&At[(wv * 16 + (lane & 15)) * 72 + k2 * 32 + (lane >> 4) * 8];
#pragma unroll
            for (int nt = 0; nt < 4; ++nt) {
                f16x8 b = *(const f16x8*)&Bt[(nt * 16 + (lane & 15)) * 72 + k2 * 32 + (lane >> 4) * 8];
                acc[nt] = __builtin_amdgcn_mfma_f32_16x16x32_f16(a, b, acc[nt], 0, 0, 0);
            }
        }
        __syncthreads();
    }
#pragma unroll
    for (int nt = 0; nt < 4; ++nt) {
        const int col = n0 + nt * 16 + (lane & 15);
        const float bv = biasScalar ? bias[0] : bias[col];
#pragma unroll
        for (int i = 0; i < 4; ++i) {
            const int row = m0 + wv * 16 + (lane >> 4) * 4 + i;
            float v = acc[nt][i] + bv;
            if (relu) v = fmaxf(v, 0.f);
            if (transOut) C[(size_t)col * ldc + row] = v;
            else          C[(size_t)row * ldc + col] = v;
        }
    }
}

__global__ void __launch_bounds__(BDIM, 1) don_gru(Params P)
{
    extern __shared__ char smem[];
    cg::grid_group grid = cg::this_grid();
    const int wg = blockIdx.x, tid = threadIdx.x;

    // ---- init: zero state buffers + output (all re-poisoned each launch) ----
    {
        const int gid = wg * BDIM + tid;              // 65536 threads
        int4* z0 = (int4*)P.h0b;                      // 65536 int4 each
        int4* z1 = (int4*)P.h1b;
        const int4 zi = {0, 0, 0, 0};
        z0[gid] = zi;
        z1[gid] = zi;
        if (gid < 4096) ((float4*)P.out)[gid] = make_float4(0, 0, 0, 0);
    }

    // ---- phase 1: branch L0 (WG 0..127) + trunk L0 elementwise (WG 128..135) ----
    if (wg < 128) {
        gemm_tile(P.x, 528, P.bWf, 528, P.bbf, 0, 1, P.brA, 512, 0, 528,
                  (wg >> 3) * 64, (wg & 7) * 64, smem);
    } else if (wg < 136) {
        const int r0 = (wg - 128) * 16;
        for (int i = tid; i < 16 * 512; i += BDIM) {
            const int r = r0 + (i >> 9), o = i & 511;
            P.trA[(size_t)r * 512 + o] = fmaxf((float)r * P.tWf[o] + P.tbf[o], 0.f);
        }
    }
    grid.sync();

    // ---- phases 2..4: stacked layers (branch no-relu on last; trunk relu always) ----
#pragma unroll 1
    for (int L = 0; L < 3; ++L) {
        const float* bi_ = (L & 1) ? P.brB : P.brA;
        float*       bo_ = (L & 1) ? P.brA : P.brB;
        const float* ti_ = (L & 1) ? P.trB : P.trA;
        float*       to_ = (L & 1) ? P.trA : P.trB;
        if (wg < 128)
            gemm_tile(bi_, 512, P.bWr + (size_t)L * 262144, 512, P.bbr + L * 512, 0,
                      (L < 2) ? 1 : 0, bo_, 512, 0, 512, (wg >> 3) * 64, (wg & 7) * 64, smem);
        else if (wg < 144)
            gemm_tile(ti_, 512, P.tWr + (size_t)L * 262144, 512, P.tbr + L * 512, 0,
                      1, to_, 512, 0, 512, ((wg - 128) >> 3) * 64, ((wg - 128) & 7) * 64, smem);
        grid.sync();
    }

    // ---- phase 5: seq^T = (branch @ trunk^T + don_bias)^T, stored [128][1024] ----
    if (wg < 32)
        gemm_tile(P.brB, 512, P.trB, 512, P.donb, 1, 0, P.seqT, 1024, 1, 512,
                  (wg >> 1) * 64, (wg & 1) * 64, smem);
    grid.sync();

    // ---- phase 6: stage recurrence weights into LDS (fp16, gate-triplet permuted, XOR-swizzled) ----
    _Float16* wts  = (_Float16*)smem;                 // [144][256] swizzled
    float* gates = (float*)(smem + 73728);            // [64][148]
    float* misc  = (float*)(smem + 73728 + 37888);    // bh0|wi0|bi0|bi1|bh1, 48 each
    const int Mb = wg >> 4, hsI = wg & 15, j0 = hsI * 16;
    {
#pragma unroll 1
        for (int rep = 0; rep < 9; ++rep) {
            const int r = rep * 16 + (tid >> 4);      // 0..143
            const int mat = r / 48, rem = r % 48;
            const int u = rem / 3, g = rem % 3;
            const int grow = g * 256 + j0 + u;
            const float* src = (mat == 0 ? P.whh0 : (mat == 1 ? P.wih1 : P.whh1))
                               + (size_t)grow * 256 + (tid & 15) * 16;
#pragma unroll
            for (int h = 0; h < 2; ++h) {
                float4 a = *(const float4*)(src + h * 8);
                float4 b = *(const float4*)(src + h * 8 + 4);
                const int q = ((tid & 15) * 2 + h) ^ (r & 7);
                *(f16x8*)&wts[r * 256 + q * 8] = cvt8(a, b);
            }
        }
        if (tid < 48) {
            const int u = tid / 3, g = tid % 3;
            const int grow = g * 256 + j0 + u;
            misc[tid]       = P.bhh0[grow];
            misc[48 + tid]  = P.wih0[grow];   // [768][1] flat
            misc[96 + tid]  = P.bih0[grow];
            misc[144 + tid] = P.bih1[grow];
            misc[192 + tid] = P.bhh1[grow];
        }
    }
    grid.sync();

    // ---- phases 7..135: recurrence, layer1 pipelined one step behind layer0 ----
    float h0f[4] = {0, 0, 0, 0}, h1f[4] = {0, 0, 0, 0};
    const int wv = tid >> 6, lane = tid & 63;
    const int am = wv * 16 + (lane & 15);   // batch row within CU tile for A-fragment
    const int m = lane, jq = wv;            // update ownership: (batch m, hidden quad jq)

#pragma unroll 1
    for (int p = 0; p <= 128; ++p) {
        const int rb = p & 1;
        const _Float16* h0r = P.h0b + rb * 262144 + Mb * 16384;
        const _Float16* h1r = P.h1b + rb * 262144 + Mb * 16384;

        // hoist all 16 A-fragment loads (16B each, coalesced) to overlap L2/L3 latency
        f16x8 a0v[8], a1v[8];
#pragma unroll
        for (int ks = 0; ks < 8; ++ks) {
            const int kc = ks * 4 + (lane >> 4);
            a0v[ks] = *(const f16x8*)(h0r + (kc * 64 + am) * 8);
            a1v[ks] = *(const f16x8*)(h1r + (kc * 64 + am) * 8);
        }
        f32x4 acc[9];
#pragma unroll
        for (int i = 0; i < 9; ++i) acc[i] = (f32x4){0.f, 0.f, 0.f, 0.f};
#pragma unroll
        for (int ks = 0; ks < 8; ++ks) {
#pragma unroll
            for (int nt = 0; nt < 9; ++nt) {   // 0..5: A=h0 (gh0,gi1), 6..8: A=h1 (gh1)
                const int rr = nt * 16 + (lane & 15);
                const int q = (ks * 4 + (lane >> 4)) ^ (rr & 7);
                const f16x8 b = *(const f16x8*)&wts[rr * 256 + q * 8];
                acc[nt] = __builtin_amdgcn_mfma_f32_16x16x32_f16(nt < 6 ? a0v[ks] : a1v[ks],
                                                                 b, acc[nt], 0, 0, 0);
            }
        }
        // scatter gate pre-activations to LDS (MFMA C layout: col=lane&15, row=(lane>>4)*4+i)
#pragma unroll
        for (int nt = 0; nt < 9; ++nt) {
            const int gn = nt * 16 + (lane & 15);
#pragma unroll
            for (int i = 0; i < 4; ++i)
                gates[(wv * 16 + (lane >> 4) * 4 + i) * 148 + gn] = acc[nt][i];
        }
        __syncthreads();

        const int wb = rb ^ 1;
        if (p < 128) {      // layer0 step p
            const float xin = P.seqT[p * 1024 + Mb * 64 + m];
#pragma unroll
            for (int i = 0; i < 4; ++i) {
                const int n3 = 3 * (jq * 4 + i);
                const float gr  = gates[m * 148 + n3 + 0] + misc[n3 + 0];
                const float gz  = gates[m * 148 + n3 + 1] + misc[n3 + 1];
                const float gnn = gates[m * 148 + n3 + 2] + misc[n3 + 2];
                const float ir  = xin * misc[48 + n3 + 0] + misc[96 + n3 + 0];
                const float iz  = xin * misc[48 + n3 + 1] + misc[96 + n3 + 1];
                const float inn = xin * misc[48 + n3 + 2] + misc[96 + n3 + 2];
                const float r_ = sigmoidf_(ir + gr);
                const float z_ = sigmoidf_(iz + gz);
                const float nn = tanhf_(inn + r_ * gnn);
                h0f[i] = (1.f - z_) * nn + z_ * h0f[i];
            }
            *(unsigned long long*)(P.h0b + wb * 262144 + Mb * 16384
                                   + ((hsI * 2 + (jq >> 1)) * 64 + m) * 8 + (jq & 1) * 4)
                = pack4(h0f);
        }
        if (p >= 1) {       // layer1 step p-1 (input hs0[p-1] = current h0 buffer)
#pragma unroll
            for (int i = 0; i < 4; ++i) {
                const int n3 = 3 * (jq * 4 + i);
                const float ir  = gates[m * 148 + 48 + n3 + 0] + misc[144 + n3 + 0];
                const float iz  = gates[m * 148 + 48 + n3 + 1] + misc[144 + n3 + 1];
                const float inn = gates[m * 148 + 48 + n3 + 2] + misc[144 + n3 + 2];
                const float hr  = gates[m * 148 + 96 + n3 + 0] + misc[192 + n3 + 0];
                const float hz  = gates[m * 148 + 96 + n3 + 1] + misc[192 + n3 + 1];
                const float hn  = gates[m * 148 + 96 + n3 + 2] + misc[192 + n3 + 2];
                const float r_ = sigmoidf_(ir + hr);
                const float z_ = sigmoidf_(iz + hz);
                const float nn = tanhf_(inn + r_ * hn);
                h1f[i] = (1.f - z_) * nn + z_ * h1f[i];
            }
            *(unsigned long long*)(P.h1b + wb * 262144 + Mb * 16384
                                   + ((hsI * 2 + (jq >> 1)) * 64 + m) * 8 + (jq & 1) * 4)
                = pack4(h1f);
        }
        __threadfence();
        grid.sync();
    }

    // ---- projection: out = h1 @ pW^T + pb (partial per CU, atomicAdd reduce) ----
    {
        float ps[16];
#pragma unroll
        for (int s = 0; s < 16; ++s) {
            float v = 0.f;
#pragma unroll
            for (int i = 0; i < 4; ++i)
                v += h1f[i] * P.pW[s * 256 + j0 + jq * 4 + i];
            ps[s] = v;
        }
        float* proj = gates;                 // reuse: [4][64][16]
#pragma unroll
        for (int s = 0; s < 16; ++s) proj[(jq * 64 + m) * 16 + s] = ps[s];
        __syncthreads();
        const int m2 = tid >> 2, s0 = (tid & 3) * 4;
#pragma unroll
        for (int si = 0; si < 4; ++si) {
            const int s = s0 + si;
            float v = proj[(0 * 64 + m2) * 16 + s] + proj[(1 * 64 + m2) * 16 + s]
                    + proj[(2 * 64 + m2) * 16 + s] + proj[(3 * 64 + m2) * 16 + s];
            if (hsI == 0) v += P.pb[s];
            atomicAdd(&P.out[(size_t)(Mb * 64 + m2) * 16 + s], v);
        }
    }
}

extern "C" void kernel_launch(void* const* d_in, const int* in_sizes, int n_in,
                              void* d_out, int out_size, void* d_ws, size_t ws_size,
                              hipStream_t stream)
{
    Params P;
    P.x    = (const float*)d_in[0];
    P.bWf  = (const float*)d_in[1];
    P.bbf  = (const float*)d_in[2];
    P.bWr  = (const float*)d_in[3];
    P.bbr  = (const float*)d_in[4];
    P.tWf  = (const float*)d_in[5];
    P.tbf  = (const float*)d_in[6];
    P.tWr  = (const float*)d_in[7];
    P.tbr  = (const float*)d_in[8];
    P.donb = (const float*)d_in[9];
    P.wih0 = (const float*)d_in[10];
    P.whh0 = (const float*)d_in[11];
    P.bih0 = (const float*)d_in[12];
    P.bhh0 = (const float*)d_in[13];
    P.wih1 = (const float*)d_in[14];
    P.whh1 = (const float*)d_in[15];
    P.bih1 = (const float*)d_in[16];
    P.bhh1 = (const float*)d_in[17];
    P.pW   = (const float*)d_in[18];
    P.pb   = (const float*)d_in[19];
    P.out  = (float*)d_out;

    char* ws = (char*)d_ws;
    P.brA  = (float*)(ws);                 // 1024*512*4 = 2 MB
    P.brB  = (float*)(ws + 2097152);       // 2 MB
    P.trA  = (float*)(ws + 4194304);       // 256 KB
    P.trB  = (float*)(ws + 4456448);       // 256 KB
    P.seqT = (float*)(ws + 4718592);       // 512 KB   [128][1024]
    P.h0b  = (_Float16*)(ws + 5242880);    // 1 MB     [2][16][32][64][8] fp16
    P.h1b  = (_Float16*)(ws + 6291456);    // 1 MB

    hipFuncSetAttribute(reinterpret_cast<const void*>(don_gru),
                        hipFuncAttributeMaxDynamicSharedMemorySize, SMEM_BYTES);
    void* args[] = { &P };
    hipLaunchCooperativeKernel(reinterpret_cast<void*>(don_gru),
                               dim3(GRID), dim3(BDIM), args, SMEM_BYTES, stream);
}

// Round 3
// 6249.662 us; speedup vs baseline: 1.3605x; 1.3605x over previous
//
#include <hip/hip_runtime.h>

typedef float f32x4 __attribute__((ext_vector_type(4)));
typedef _Float16 f16x8 __attribute__((ext_vector_type(8)));

#define BDIM 256
#define GRID 256
// LDS layout (recurrence): wts 73728 B | gates 64*149*4=38144 B | misc 240*4=960 B
#define SMEM_BYTES (73728 + 38144 + 960)
#define BAR_OFF 7340032u

struct Params {
    const float *x, *bWf, *bbf, *bWr, *bbr;
    const float *tWf, *tbf, *tWr, *tbr, *donb;
    const float *wih0, *whh0, *bih0, *bhh0;
    const float *wih1, *whh1, *bih1, *bhh1;
    const float *pW, *pb;
    float *out;
    float *brA, *brB, *trA, *trB, *seqT;
    _Float16 *h0b, *h1b;   // fp16 ping-pong state buffers, fragment-ready layout
    unsigned *mbar, *gbar; // barrier counters (memset to 0 before launch)
};

__device__ __forceinline__ f16x8 cvt8(float4 a, float4 b) {
    f16x8 r;
    r[0] = (_Float16)a.x; r[1] = (_Float16)a.y; r[2] = (_Float16)a.z; r[3] = (_Float16)a.w;
    r[4] = (_Float16)b.x; r[5] = (_Float16)b.y; r[6] = (_Float16)b.z; r[7] = (_Float16)b.w;
    return r;
}

__device__ __forceinline__ unsigned short f2hbits(float x) {
    union { _Float16 h; unsigned short u; } v; v.h = (_Float16)x; return v.u;
}

__device__ __forceinline__ unsigned long long pack4(const float* v) {
    return  (unsigned long long)f2hbits(v[0])
         | ((unsigned long long)f2hbits(v[1]) << 16)
         | ((unsigned long long)f2hbits(v[2]) << 32)
         | ((unsigned long long)f2hbits(v[3]) << 48);
}

__device__ __forceinline__ float sigmoidf_(float x) { return 1.f / (1.f + __expf(-x)); }
__device__ __forceinline__ float tanhf_(float x)    { return 1.f - 2.f / (__expf(2.f * x) + 1.f); }

// Monotonic spin barrier: `nmem` arrivals expected per use; target = use_index*nmem.
__device__ __forceinline__ void barwait(unsigned* c, unsigned target) {
    __threadfence();                                   // release: flush prior writes
    __syncthreads();
    if (threadIdx.x == 0) {
        __hip_atomic_fetch_add(c, 1u, __ATOMIC_RELEASE, __HIP_MEMORY_SCOPE_AGENT);
        while (__hip_atomic_load(c, __ATOMIC_ACQUIRE, __HIP_MEMORY_SCOPE_AGENT) < target)
            __builtin_amdgcn_s_sleep(1);
    }
    __syncthreads();
    __threadfence();                                   // acquire: invalidate L1
}

// Generic 64x64-tile GEMM: C[m0..+64, n0..+64] = op(A[M,K] @ W[N,K]^T + bias)
__device__ void gemm_tile(const float* __restrict__ A, int lda,
                          const float* __restrict__ W, int ldw,
                          const float* __restrict__ bias, int biasScalar,
                          int relu, float* __restrict__ C, int ldc, int transOut,
                          int K, int m0, int n0, char* smem)
{
    _Float16* At = (_Float16*)smem;            // [64][72]
    _Float16* Bt = (_Float16*)smem + 64 * 72;  // [64][72]
    const int tid = threadIdx.x;
    const int wv = tid >> 6, lane = tid & 63;
    f32x4 acc[4];
#pragma unroll
    for (int i = 0; i < 4; ++i) acc[i] = (f32x4){0.f, 0.f, 0.f, 0.f};

    const int srow = tid >> 2, sc0 = (tid & 3) * 16;
    for (int kc = 0; kc < K; kc += 64) {
        const float* asrc = A + (size_t)(m0 + srow) * lda + kc + sc0;
        const float* wsrc = W + (size_t)(n0 + srow) * ldw + kc + sc0;
#pragma unroll
        for (int h = 0; h < 2; ++h) {
            float4 v0 = make_float4(0, 0, 0, 0), v1 = v0, u0 = v0, u1 = v0;
            if (kc + sc0 + h * 8 < K) {        // K % 8 == 0 for all our shapes
                v0 = *(const float4*)(asrc + h * 8);
                v1 = *(const float4*)(asrc + h * 8 + 4);
                u0 = *(const float4*)(wsrc + h * 8);
                u1 = *(const float4*)(wsrc + h * 8 + 4);
            }
            *(f16x8*)&At[srow * 72 + sc0 + h * 8] = cvt8(v0, v1);
            *(f16x8*)&Bt[srow * 72 + sc0 + h * 8] = cvt8(u0, u1);
        }
        __syncthreads();
#pragma unroll
        for (int k2 = 0; k2 < 2; ++k2) {
            f16x8 a = *(const f16x8*)&At[(wv * 16 + (lane & 15)) * 72 + k2 * 32 + (lane >> 4) * 8];
#pragma unroll
            for (int nt = 0; nt < 4; ++nt) {
                f16x8 b = *(const f16x8*)&Bt[(nt * 16 + (lane & 15)) * 72 + k2 * 32 + (lane >> 4) * 8];
                acc[nt] = __builtin_amdgcn_mfma_f32_16x16x32_f16(a, b, acc[nt], 0, 0, 0);
            }
        }
        __syncthreads();
    }
#pragma unroll
    for (int nt = 0; nt < 4; ++nt) {
        const int col = n0 + nt * 16 + (lane & 15);
        const float bv = biasScalar ? bias[0] : bias[col];
#pragma unroll
        for (int i = 0; i < 4; ++i) {
            const int row = m0 + wv * 16 + (lane >> 4) * 4 + i;
            float v = acc[nt][i] + bv;
            if (relu) v = fmaxf(v, 0.f);
            if (transOut) C[(size_t)col * ldc + row] = v;
            else          C[(size_t)row * ldc + col] = v;
        }
    }
}

__global__ void __launch_bounds__(BDIM, 1) don_gru(Params P)
{
    extern __shared__ char smem[];
    const int wg = blockIdx.x, tid = threadIdx.x;
    // XCD-local group mapping: all 16 members of group Mb sit on XCD (wg&7).
    const int xcd = wg & 7, slot = wg >> 3;           // slot 0..31
    const int Mb  = xcd + ((slot >> 4) << 3);         // 0..15
    const int hsI = slot & 15, j0 = hsI * 16;
    unsigned* mc = P.mbar + Mb * 32;                  // group counter, own 128B line
    unsigned gph = 1;

    // ---- init: zero state buffers + output ----
    {
        const int gid = wg * BDIM + tid;              // 65536 threads
        int4* z0 = (int4*)P.h0b;
        int4* z1 = (int4*)P.h1b;
        const int4 zi = {0, 0, 0, 0};
        z0[gid] = zi;
        z1[gid] = zi;
        if (gid < 4096) ((float4*)P.out)[gid] = make_float4(0, 0, 0, 0);
    }

    // ---- phase 1: branch L0 (WG 0..127) + trunk L0 elementwise (WG 128..135) ----
    if (wg < 128) {
        gemm_tile(P.x, 528, P.bWf, 528, P.bbf, 0, 1, P.brA, 512, 0, 528,
                  (wg >> 3) * 64, (wg & 7) * 64, smem);
    } else if (wg < 136) {
        const int r0 = (wg - 128) * 16;
        for (int i = tid; i < 16 * 512; i += BDIM) {
            const int r = r0 + (i >> 9), o = i & 511;
            P.trA[(size_t)r * 512 + o] = fmaxf((float)r * P.tWf[o] + P.tbf[o], 0.f);
        }
    }
    barwait(P.gbar, 256u * gph); ++gph;

    // ---- phases 2..4: stacked layers ----
#pragma unroll 1
    for (int L = 0; L < 3; ++L) {
        const float* bi_ = (L & 1) ? P.brB : P.brA;
        float*       bo_ = (L & 1) ? P.brA : P.brB;
        const float* ti_ = (L & 1) ? P.trB : P.trA;
        float*       to_ = (L & 1) ? P.trA : P.trB;
        if (wg < 128)
            gemm_tile(bi_, 512, P.bWr + (size_t)L * 262144, 512, P.bbr + L * 512, 0,
                      (L < 2) ? 1 : 0, bo_, 512, 0, 512, (wg >> 3) * 64, (wg & 7) * 64, smem);
        else if (wg < 144)
            gemm_tile(ti_, 512, P.tWr + (size_t)L * 262144, 512, P.tbr + L * 512, 0,
                      1, to_, 512, 0, 512, ((wg - 128) >> 3) * 64, ((wg - 128) & 7) * 64, smem);
        barwait(P.gbar, 256u * gph); ++gph;
    }

    // ---- phase 5: seq^T = (branch @ trunk^T + don_bias)^T, stored [128][1024] ----
    if (wg < 32)
        gemm_tile(P.brB, 512, P.trB, 512, P.donb, 1, 0, P.seqT, 1024, 1, 512,
                  (wg >> 1) * 64, (wg & 1) * 64, smem);
    barwait(P.gbar, 256u * gph); ++gph;

    // ---- phase 6: stage recurrence weights into LDS (per-WG, no cross-WG sync needed) ----
    _Float16* wts  = (_Float16*)smem;                 // [144][256] swizzled
    float* gates = (float*)(smem + 73728);            // [64][149]
    float* misc  = (float*)(smem + 73728 + 38144);    // bh0|wi0|bi0|bi1|bh1, 48 each
    {
#pragma unroll 1
        for (int rep = 0; rep < 9; ++rep) {
            const int r = rep * 16 + (tid >> 4);      // 0..143
            const int mat = r / 48, rem = r % 48;
            const int u = rem / 3, g = rem % 3;
            const int grow = g * 256 + j0 + u;
            const float* src = (mat == 0 ? P.whh0 : (mat == 1 ? P.wih1 : P.whh1))
                               + (size_t)grow * 256 + (tid & 15) * 16;
#pragma unroll
            for (int h = 0; h < 2; ++h) {
                float4 a = *(const float4*)(src + h * 8);
                float4 b = *(const float4*)(src + h * 8 + 4);
                const int q = ((tid & 15) * 2 + h) ^ (r & 7);
                *(f16x8*)&wts[r * 256 + q * 8] = cvt8(a, b);
            }
        }
        if (tid < 48) {
            const int u = tid / 3, g = tid % 3;
            const int grow = g * 256 + j0 + u;
            misc[tid]       = P.bhh0[grow];
            misc[48 + tid]  = P.wih0[grow];   // [768][1] flat
            misc[96 + tid]  = P.bih0[grow];
            misc[144 + tid] = P.bih1[grow];
            misc[192 + tid] = P.bhh1[grow];
        }
    }
    __syncthreads();

    // ---- phases 7..135: recurrence, layer1 pipelined one step behind layer0 ----
    float h0f[4] = {0, 0, 0, 0}, h1f[4] = {0, 0, 0, 0};
    const int wv = tid >> 6, lane = tid & 63;
    const int am = wv * 16 + (lane & 15);
    const int m = lane, jq = wv;

#pragma unroll 1
    for (int p = 0; p <= 128; ++p) {
        const int rb = p & 1;
        const _Float16* h0r = P.h0b + rb * 262144 + Mb * 16384;
        const _Float16* h1r = P.h1b + rb * 262144 + Mb * 16384;

        f16x8 a0v[8], a1v[8];
#pragma unroll
        for (int ks = 0; ks < 8; ++ks) {
            const int kc = ks * 4 + (lane >> 4);
            a0v[ks] = *(const f16x8*)(h0r + (kc * 64 + am) * 8);
            a1v[ks] = *(const f16x8*)(h1r + (kc * 64 + am) * 8);
        }
        f32x4 acc[9];
#pragma unroll
        for (int i = 0; i < 9; ++i) acc[i] = (f32x4){0.f, 0.f, 0.f, 0.f};
#pragma unroll
        for (int ks = 0; ks < 8; ++ks) {
#pragma unroll
            for (int nt = 0; nt < 9; ++nt) {   // 0..5: A=h0 (gh0,gi1), 6..8: A=h1 (gh1)
                const int rr = nt * 16 + (lane & 15);
                const int q = (ks * 4 + (lane >> 4)) ^ (rr & 7);
                const f16x8 b = *(const f16x8*)&wts[rr * 256 + q * 8];
                acc[nt] = __builtin_amdgcn_mfma_f32_16x16x32_f16(nt < 6 ? a0v[ks] : a1v[ks],
                                                                 b, acc[nt], 0, 0, 0);
            }
        }
#pragma unroll
        for (int nt = 0; nt < 9; ++nt) {
            const int gn = nt * 16 + (lane & 15);
#pragma unroll
            for (int i = 0; i < 4; ++i)
                gates[(wv * 16 + (lane >> 4) * 4 + i) * 149 + gn] = acc[nt][i];
        }
        __syncthreads();

        const int wb = rb ^ 1;
        if (p < 128) {      // layer0 step p
            const float xin = P.seqT[p * 1024 + Mb * 64 + m];
#pragma unroll
            for (int i = 0; i < 4; ++i) {
                const int n3 = 3 * (jq * 4 + i);
                const float gr  = gates[m * 149 + n3 + 0] + misc[n3 + 0];
                const float gz  = gates[m * 149 + n3 + 1] + misc[n3 + 1];
                const float gnn = gates[m * 149 + n3 + 2] + misc[n3 + 2];
                const float ir  = xin * misc[48 + n3 + 0] + misc[96 + n3 + 0];
                const float iz  = xin * misc[48 + n3 + 1] + misc[96 + n3 + 1];
                const float inn = xin * misc[48 + n3 + 2] + misc[96 + n3 + 2];
                const float r_ = sigmoidf_(ir + gr);
                const float z_ = sigmoidf_(iz + gz);
                const float nn = tanhf_(inn + r_ * gnn);
                h0f[i] = (1.f - z_) * nn + z_ * h0f[i];
            }
            *(unsigned long long*)(P.h0b + wb * 262144 + Mb * 16384
                                   + ((hsI * 2 + (jq >> 1)) * 64 + m) * 8 + (jq & 1) * 4)
                = pack4(h0f);
        }
        if (p >= 1) {       // layer1 step p-1
#pragma unroll
            for (int i = 0; i < 4; ++i) {
                const int n3 = 3 * (jq * 4 + i);
                const float ir  = gates[m * 149 + 48 + n3 + 0] + misc[144 + n3 + 0];
                const float iz  = gates[m * 149 + 48 + n3 + 1] + misc[144 + n3 + 1];
                const float inn = gates[m * 149 + 48 + n3 + 2] + misc[144 + n3 + 2];
                const float hr  = gates[m * 149 + 96 + n3 + 0] + misc[192 + n3 + 0];
                const float hz  = gates[m * 149 + 96 + n3 + 1] + misc[192 + n3 + 1];
                const float hn  = gates[m * 149 + 96 + n3 + 2] + misc[192 + n3 + 2];
                const float r_ = sigmoidf_(ir + hr);
                const float z_ = sigmoidf_(iz + hz);
                const float nn = tanhf_(inn + r_ * hn);
                h1f[i] = (1.f - z_) * nn + z_ * h1f[i];
            }
            *(unsigned long long*)(P.h1b + wb * 262144 + Mb * 16384
                                   + ((hsI * 2 + (jq >> 1)) * 64 + m) * 8 + (jq & 1) * 4)
                = pack4(h1f);
        }
        barwait(mc, 16u * (unsigned)(p + 1));   // 16-WG XCD-local group barrier
    }

    // ---- projection: out = h1 @ pW^T + pb (partial per CU, atomicAdd reduce) ----
    {
        float ps[16];
#pragma unroll
        for (int s = 0; s < 16; ++s) {
            float v = 0.f;
#pragma unroll
            for (int i = 0; i < 4; ++i)
                v += h1f[i] * P.pW[s * 256 + j0 + jq * 4 + i];
            ps[s] = v;
        }
        float* proj = gates;                 // reuse: [4][64][16]
#pragma unroll
        for (int s = 0; s < 16; ++s) proj[(jq * 64 + m) * 16 + s] = ps[s];
        __syncthreads();
        const int m2 = tid >> 2, s0 = (tid & 3) * 4;
#pragma unroll
        for (int si = 0; si < 4; ++si) {
            const int s = s0 + si;
            float v = proj[(0 * 64 + m2) * 16 + s] + proj[(1 * 64 + m2) * 16 + s]
                    + proj[(2 * 64 + m2) * 16 + s] + proj[(3 * 64 + m2) * 16 + s];
            if (hsI == 0) v += P.pb[s];
            atomicAdd(&P.out[(size_t)(Mb * 64 + m2) * 16 + s], v);
        }
    }
}

extern "C" void kernel_launch(void* const* d_in, const int* in_sizes, int n_in,
                              void* d_out, int out_size, void* d_ws, size_t ws_size,
                              hipStream_t stream)
{
    Params P;
    P.x    = (const float*)d_in[0];
    P.bWf  = (const float*)d_in[1];
    P.bbf  = (const float*)d_in[2];
    P.bWr  = (const float*)d_in[3];
    P.bbr  = (const float*)d_in[4];
    P.tWf  = (const float*)d_in[5];
    P.tbf  = (const float*)d_in[6];
    P.tWr  = (const float*)d_in[7];
    P.tbr  = (const float*)d_in[8];
    P.donb = (const float*)d_in[9];
    P.wih0 = (const float*)d_in[10];
    P.whh0 = (const float*)d_in[11];
    P.bih0 = (const float*)d_in[12];
    P.bhh0 = (const float*)d_in[13];
    P.wih1 = (const float*)d_in[14];
    P.whh1 = (const float*)d_in[15];
    P.bih1 = (const float*)d_in[16];
    P.bhh1 = (const float*)d_in[17];
    P.pW   = (const float*)d_in[18];
    P.pb   = (const float*)d_in[19];
    P.out  = (float*)d_out;

    char* ws = (char*)d_ws;
    P.brA  = (float*)(ws);                 // 2 MB
    P.brB  = (float*)(ws + 2097152);       // 2 MB
    P.trA  = (float*)(ws + 4194304);       // 256 KB
    P.trB  = (float*)(ws + 4456448);       // 256 KB
    P.seqT = (float*)(ws + 4718592);       // 512 KB   [128][1024]
    P.h0b  = (_Float16*)(ws + 5242880);    // 1 MB
    P.h1b  = (_Float16*)(ws + 6291456);    // 1 MB
    P.mbar = (unsigned*)(ws + BAR_OFF);    // 16 counters, 128B stride
    P.gbar = (unsigned*)(ws + BAR_OFF + 2048);

    hipMemsetAsync((void*)(ws + BAR_OFF), 0, 4096, stream);   // zero barrier counters
    hipFuncSetAttribute(reinterpret_cast<const void*>(don_gru),
                        hipFuncAttributeMaxDynamicSharedMemorySize, SMEM_BYTES);
    void* args[] = { &P };
    hipLaunchCooperativeKernel(reinterpret_cast<void*>(don_gru),
                               dim3(GRID), dim3(BDIM), args, SMEM_BYTES, stream);
}

// Round 8
// 981.767 us; speedup vs baseline: 8.6603x; 6.3657x over previous
//
#include <hip/hip_runtime.h>

typedef float f32x4 __attribute__((ext_vector_type(4)));
typedef _Float16 f16x8 __attribute__((ext_vector_type(8)));
typedef unsigned long long u64;

#define BDIM 256
#define GRID 256
// LDS: wts 73728 | gates 64*149*4=38144 | misc 960 | seqL 128*64*4=32768  => 145600
#define SMEM_BYTES 145600
#define BAR_OFF 7340032u
#define AGENT __HIP_MEMORY_SCOPE_AGENT

struct Params {
    const float *x, *bWf, *bbf, *bWr, *bbr;
    const float *tWf, *tbf, *tWr, *tbr, *donb;
    const float *wih0, *whh0, *bih0, *bhh0;
    const float *wih1, *whh1, *bih1, *bhh1;
    const float *pW, *pb;
    float *out;
    float *brA, *brB, *trA, *trB, *seqT;
    _Float16 *h0b, *h1b;   // fp16 ping-pong state buffers, fragment-ready layout
    unsigned *mbar, *gbar; // barrier counters (memset to 0 before launch)
};

// ---- coherent (IF$-through, no L2 maintenance) access helpers ----
__device__ __forceinline__ void st64c(void* p, u64 v) {
    __hip_atomic_store((u64*)p, v, __ATOMIC_RELAXED, AGENT);
}
__device__ __forceinline__ u64 ld64c(const void* p) {
    return __hip_atomic_load((const u64*)p, __ATOMIC_RELAXED, AGENT);
}
__device__ __forceinline__ void st32c(float* p, float v) {
    union { float f; unsigned u; } c; c.f = v;
    __hip_atomic_store((unsigned*)p, c.u, __ATOMIC_RELAXED, AGENT);
}
__device__ __forceinline__ float ld32c(const float* p) {
    union { unsigned u; float f; } c;
    c.u = __hip_atomic_load((const unsigned*)p, __ATOMIC_RELAXED, AGENT);
    return c.f;
}
__device__ __forceinline__ float4 ld128c(const float* p) {   // 16B via 2x8B
    union { u64 q[2]; float4 v; } c;
    c.q[0] = ld64c(p); c.q[1] = ld64c(p + 2);
    return c.v;
}
__device__ __forceinline__ f16x8 ldf16x8c(const _Float16* p) {
    union { u64 q[2]; f16x8 v; } c;
    c.q[0] = ld64c(p); c.q[1] = ld64c(p + 4);
    return c.v;
}

__device__ __forceinline__ f16x8 cvt8(float4 a, float4 b) {
    f16x8 r;
    r[0] = (_Float16)a.x; r[1] = (_Float16)a.y; r[2] = (_Float16)a.z; r[3] = (_Float16)a.w;
    r[4] = (_Float16)b.x; r[5] = (_Float16)b.y; r[6] = (_Float16)b.z; r[7] = (_Float16)b.w;
    return r;
}

__device__ __forceinline__ unsigned short f2hbits(float x) {
    union { _Float16 h; unsigned short u; } v; v.h = (_Float16)x; return v.u;
}

__device__ __forceinline__ u64 pack4(const float* v) {
    return  (u64)f2hbits(v[0])
         | ((u64)f2hbits(v[1]) << 16)
         | ((u64)f2hbits(v[2]) << 32)
         | ((u64)f2hbits(v[3]) << 48);
}

__device__ __forceinline__ float sigmoidf_(float x) { return 1.f / (1.f + __expf(-x)); }
__device__ __forceinline__ float tanhf_(float x)    { return 1.f - 2.f / (__expf(2.f * x) + 1.f); }

// Fence-free monotonic barrier: all cross-WG data moves via sc1 ops, so no
// buffer_wbl2/buffer_inv needed — just drain stores, count arrivals at IF$.
// Bounded spin (2^20 iters ~ 20ms): converts a broken barrier into a wrong
// answer (diagnosable absmax failure) instead of a container-killing hang.
__device__ __forceinline__ void barwait(unsigned* c, unsigned target) {
    asm volatile("s_waitcnt vmcnt(0)" ::: "memory");   // per-wave: stores reached IF$
    __syncthreads();                                   // all waves drained
    if (threadIdx.x == 0) {
        __hip_atomic_fetch_add(c, 1u, __ATOMIC_RELAXED, AGENT);
        unsigned guard = 0;
        while (__hip_atomic_load(c, __ATOMIC_RELAXED, AGENT) < target) {
            __builtin_amdgcn_s_sleep(1);
            if (++guard > (1u << 20)) break;           // safety: never hang
        }
    }
    __syncthreads();
}

// Generic 64x64-tile GEMM: C[m0..+64, n0..+64] = op(A[M,K] @ W[N,K]^T + bias)
// A: sc1-coherent loads if aCoh (device-produced activations), else plain (inputs).
// W/bias: plain cached loads (kernel inputs). C: sc1 stores (cross-WG consumed).
__device__ void gemm_tile(const float* __restrict__ A, int lda, int aCoh,
                          const float* __restrict__ W, int ldw,
                          const float* __restrict__ bias, int biasScalar,
                          int relu, float* __restrict__ C, int ldc, int transOut,
                          int K, int m0, int n0, char* smem)
{
    _Float16* At = (_Float16*)smem;            // [64][72]
    _Float16* Bt = (_Float16*)smem + 64 * 72;  // [64][72]
    const int tid = threadIdx.x;
    const int wv = tid >> 6, lane = tid & 63;
    f32x4 acc[4];
#pragma unroll
    for (int i = 0; i < 4; ++i) acc[i] = (f32x4){0.f, 0.f, 0.f, 0.f};

    const int srow = tid >> 2, sc0 = (tid & 3) * 16;
    for (int kc = 0; kc < K; kc += 64) {
        const float* asrc = A + (size_t)(m0 + srow) * lda + kc + sc0;
        const float* wsrc = W + (size_t)(n0 + srow) * ldw + kc + sc0;
#pragma unroll
        for (int h = 0; h < 2; ++h) {
            float4 v0 = make_float4(0, 0, 0, 0), v1 = v0, u0 = v0, u1 = v0;
            if (kc + sc0 + h * 8 < K) {        // K % 8 == 0 for all our shapes
                if (aCoh) {
                    v0 = ld128c(asrc + h * 8);
                    v1 = ld128c(asrc + h * 8 + 4);
                } else {
                    v0 = *(const float4*)(asrc + h * 8);
                    v1 = *(const float4*)(asrc + h * 8 + 4);
                }
                u0 = *(const float4*)(wsrc + h * 8);
                u1 = *(const float4*)(wsrc + h * 8 + 4);
            }
            *(f16x8*)&At[srow * 72 + sc0 + h * 8] = cvt8(v0, v1);
            *(f16x8*)&Bt[srow * 72 + sc0 + h * 8] = cvt8(u0, u1);
        }
        __syncthreads();
#pragma unroll
        for (int k2 = 0; k2 < 2; ++k2) {
            f16x8 a = *(const f16x8*)&At[(wv * 16 + (lane & 15)) * 72 + k2 * 32 + (lane >> 4) * 8];
#pragma unroll
            for (int nt = 0; nt < 4; ++nt) {
                f16x8 b = *(const f16x8*)&Bt[(nt * 16 + (lane & 15)) * 72 + k2 * 32 + (lane >> 4) * 8];
                acc[nt] = __builtin_amdgcn_mfma_f32_16x16x32_f16(a, b, acc[nt], 0, 0, 0);
            }
        }
        __syncthreads();
    }
#pragma unroll
    for (int nt = 0; nt < 4; ++nt) {
        const int col = n0 + nt * 16 + (lane & 15);
        const float bv = biasScalar ? bias[0] : bias[col];
#pragma unroll
        for (int i = 0; i < 4; ++i) {
            const int row = m0 + wv * 16 + (lane >> 4) * 4 + i;
            float v = acc[nt][i] + bv;
            if (relu) v = fmaxf(v, 0.f);
            if (transOut) st32c(&C[(size_t)col * ldc + row], v);
            else          st32c(&C[(size_t)row * ldc + col], v);
        }
    }
}

__global__ void __launch_bounds__(BDIM, 1) don_gru(Params P)
{
    extern __shared__ char smem[];
    const int wg = blockIdx.x, tid = threadIdx.x;
    // Group mapping (heuristic XCD-locality; correctness independent of it).
    const int xcd = wg & 7, slot = wg >> 3;
    const int Mb  = xcd + ((slot >> 4) << 3);         // 0..15
    const int hsI = slot & 15, j0 = hsI * 16;
    unsigned* mc = P.mbar + Mb * 32;                  // group counter, own 128B line
    unsigned gph = 1;

    // ---- init: zero state buffers + output via coherent stores ----
    {
        const int gid = wg * BDIM + tid;              // 65536 threads
        st64c((u64*)P.h0b + gid * 2, 0ull);
        st64c((u64*)P.h0b + gid * 2 + 1, 0ull);
        st64c((u64*)P.h1b + gid * 2, 0ull);
        st64c((u64*)P.h1b + gid * 2 + 1, 0ull);
        if (gid < 4096) {
            st64c((u64*)P.out + gid * 2, 0ull);
            st64c((u64*)P.out + gid * 2 + 1, 0ull);
        }
    }

    // ---- phase 1: branch L0 (WG 0..127) + trunk L0 elementwise (WG 128..135) ----
    if (wg < 128) {
        gemm_tile(P.x, 528, 0, P.bWf, 528, P.bbf, 0, 1, P.brA, 512, 0, 528,
                  (wg >> 3) * 64, (wg & 7) * 64, smem);
    } else if (wg < 136) {
        const int r0 = (wg - 128) * 16;
        for (int i = tid; i < 16 * 512; i += BDIM) {
            const int r = r0 + (i >> 9), o = i & 511;
            st32c(&P.trA[(size_t)r * 512 + o], fmaxf((float)r * P.tWf[o] + P.tbf[o], 0.f));
        }
    }
    barwait(P.gbar, 256u * gph); ++gph;

    // ---- phases 2..4: stacked layers ----
#pragma unroll 1
    for (int L = 0; L < 3; ++L) {
        const float* bi_ = (L & 1) ? P.brB : P.brA;
        float*       bo_ = (L & 1) ? P.brA : P.brB;
        const float* ti_ = (L & 1) ? P.trB : P.trA;
        float*       to_ = (L & 1) ? P.trA : P.trB;
        if (wg < 128)
            gemm_tile(bi_, 512, 1, P.bWr + (size_t)L * 262144, 512, P.bbr + L * 512, 0,
                      (L < 2) ? 1 : 0, bo_, 512, 0, 512, (wg >> 3) * 64, (wg & 7) * 64, smem);
        else if (wg < 144)
            gemm_tile(ti_, 512, 1, P.tWr + (size_t)L * 262144, 512, P.tbr + L * 512, 0,
                      1, to_, 512, 0, 512, ((wg - 128) >> 3) * 64, ((wg - 128) & 7) * 64, smem);
        barwait(P.gbar, 256u * gph); ++gph;
    }

    // ---- phase 5: seq^T = (branch @ trunk^T + don_bias)^T, stored [128][1024] ----
    if (wg < 32)
        gemm_tile(P.brB, 512, 1, P.trB, 512, P.donb, 1, 0, P.seqT, 1024, 1, 512,
                  (wg >> 1) * 64, (wg & 1) * 64, smem);
    barwait(P.gbar, 256u * gph); ++gph;

    // ---- phase 6: stage weights + seq slice into LDS (per-WG) ----
    _Float16* wts  = (_Float16*)smem;                 // [144][256] swizzled
    float* gates = (float*)(smem + 73728);            // [64][149]
    float* misc  = (float*)(smem + 111872);           // bh0|wi0|bi0|bi1|bh1, 48 each
    float* seqL  = (float*)(smem + 112832);           // [128][64]
    {
#pragma unroll 1
        for (int rep = 0; rep < 9; ++rep) {
            const int r = rep * 16 + (tid >> 4);      // 0..143
            const int mat = r / 48, rem = r % 48;
            const int u = rem / 3, g = rem % 3;
            const int grow = g * 256 + j0 + u;
            const float* src = (mat == 0 ? P.whh0 : (mat == 1 ? P.wih1 : P.whh1))
                               + (size_t)grow * 256 + (tid & 15) * 16;
#pragma unroll
            for (int h = 0; h < 2; ++h) {
                float4 a = *(const float4*)(src + h * 8);
                float4 b = *(const float4*)(src + h * 8 + 4);
                const int q = ((tid & 15) * 2 + h) ^ (r & 7);
                *(f16x8*)&wts[r * 256 + q * 8] = cvt8(a, b);
            }
        }
        for (int i = tid; i < 128 * 64; i += BDIM)    // seq slice: 32KB, coalesced
            seqL[i] = ld32c(P.seqT + (size_t)(i >> 6) * 1024 + Mb * 64 + (i & 63));
        if (tid < 48) {
            const int u = tid / 3, g = tid % 3;
            const int grow = g * 256 + j0 + u;
            misc[tid]       = P.bhh0[grow];
            misc[48 + tid]  = P.wih0[grow];   // [768][1] flat
            misc[96 + tid]  = P.bih0[grow];
            misc[144 + tid] = P.bih1[grow];
            misc[192 + tid] = P.bhh1[grow];
        }
    }
    __syncthreads();

    // ---- phases 7..135: recurrence, layer1 pipelined one step behind layer0 ----
    float h0f[4] = {0, 0, 0, 0}, h1f[4] = {0, 0, 0, 0};
    const int wv = tid >> 6, lane = tid & 63;
    const int am = wv * 16 + (lane & 15);
    const int m = lane, jq = wv;

#pragma unroll 1
    for (int p = 0; p <= 128; ++p) {
        const int rb = p & 1;
        const _Float16* h0r = P.h0b + rb * 262144 + Mb * 16384;
        const _Float16* h1r = P.h1b + rb * 262144 + Mb * 16384;

        f16x8 a0v[8], a1v[8];
#pragma unroll
        for (int ks = 0; ks < 8; ++ks) {
            const int kc = ks * 4 + (lane >> 4);
            a0v[ks] = ldf16x8c(h0r + (kc * 64 + am) * 8);
            a1v[ks] = ldf16x8c(h1r + (kc * 64 + am) * 8);
        }
        f32x4 acc[9];
#pragma unroll
        for (int i = 0; i < 9; ++i) acc[i] = (f32x4){0.f, 0.f, 0.f, 0.f};
#pragma unroll
        for (int ks = 0; ks < 8; ++ks) {
#pragma unroll
            for (int nt = 0; nt < 9; ++nt) {   // 0..5: A=h0 (gh0,gi1), 6..8: A=h1 (gh1)
                const int rr = nt * 16 + (lane & 15);
                const int q = (ks * 4 + (lane >> 4)) ^ (rr & 7);
                const f16x8 b = *(const f16x8*)&wts[rr * 256 + q * 8];
                acc[nt] = __builtin_amdgcn_mfma_f32_16x16x32_f16(nt < 6 ? a0v[ks] : a1v[ks],
                                                                 b, acc[nt], 0, 0, 0);
            }
        }
#pragma unroll
        for (int nt = 0; nt < 9; ++nt) {
            const int gn = nt * 16 + (lane & 15);
#pragma unroll
            for (int i = 0; i < 4; ++i)
                gates[(wv * 16 + (lane >> 4) * 4 + i) * 149 + gn] = acc[nt][i];
        }
        __syncthreads();

        const int wb = rb ^ 1;
        if (p < 128) {      // layer0 step p
            const float xin = seqL[p * 64 + m];
#pragma unroll
            for (int i = 0; i < 4; ++i) {
                const int n3 = 3 * (jq * 4 + i);
                const float gr  = gates[m * 149 + n3 + 0] + misc[n3 + 0];
                const float gz  = gates[m * 149 + n3 + 1] + misc[n3 + 1];
                const float gnn = gates[m * 149 + n3 + 2] + misc[n3 + 2];
                const float ir  = xin * misc[48 + n3 + 0] + misc[96 + n3 + 0];
                const float iz  = xin * misc[48 + n3 + 1] + misc[96 + n3 + 1];
                const float inn = xin * misc[48 + n3 + 2] + misc[96 + n3 + 2];
                const float r_ = sigmoidf_(ir + gr);
                const float z_ = sigmoidf_(iz + gz);
                const float nn = tanhf_(inn + r_ * gnn);
                h0f[i] = (1.f - z_) * nn + z_ * h0f[i];
            }
            st64c(P.h0b + wb * 262144 + Mb * 16384
                  + ((hsI * 2 + (jq >> 1)) * 64 + m) * 8 + (jq & 1) * 4, pack4(h0f));
        }
        if (p >= 1) {       // layer1 step p-1
#pragma unroll
            for (int i = 0; i < 4; ++i) {
                const int n3 = 3 * (jq * 4 + i);
                const float ir  = gates[m * 149 + 48 + n3 + 0] + misc[144 + n3 + 0];
                const float iz  = gates[m * 149 + 48 + n3 + 1] + misc[144 + n3 + 1];
                const float inn = gates[m * 149 + 48 + n3 + 2] + misc[144 + n3 + 2];
                const float hr  = gates[m * 149 + 96 + n3 + 0] + misc[192 + n3 + 0];
                const float hz  = gates[m * 149 + 96 + n3 + 1] + misc[192 + n3 + 1];
                const float hn  = gates[m * 149 + 96 + n3 + 2] + misc[192 + n3 + 2];
                const float r_ = sigmoidf_(ir + hr);
                const float z_ = sigmoidf_(iz + hz);
                const float nn = tanhf_(inn + r_ * hn);
                h1f[i] = (1.f - z_) * nn + z_ * h1f[i];
            }
            st64c(P.h1b + wb * 262144 + Mb * 16384
                  + ((hsI * 2 + (jq >> 1)) * 64 + m) * 8 + (jq & 1) * 4, pack4(h1f));
        }
        barwait(mc, 16u * (unsigned)(p + 1));   // 16-WG group barrier (fence-free)
    }

    // ---- projection: out = h1 @ pW^T + pb (partial per CU, atomicAdd reduce) ----
    {
        float ps[16];
#pragma unroll
        for (int s = 0; s < 16; ++s) {
            float v = 0.f;
#pragma unroll
            for (int i = 0; i < 4; ++i)
                v += h1f[i] * P.pW[s * 256 + j0 + jq * 4 + i];
            ps[s] = v;
        }
        float* proj = gates;                 // reuse: [4][64][16]
#pragma unroll
        for (int s = 0; s < 16; ++s) proj[(jq * 64 + m) * 16 + s] = ps[s];
        __syncthreads();
        const int m2 = tid >> 2, s0 = (tid & 3) * 4;
#pragma unroll
        for (int si = 0; si < 4; ++si) {
            const int s = s0 + si;
            float v = proj[(0 * 64 + m2) * 16 + s] + proj[(1 * 64 + m2) * 16 + s]
                    + proj[(2 * 64 + m2) * 16 + s] + proj[(3 * 64 + m2) * 16 + s];
            if (hsI == 0) v += P.pb[s];
            atomicAdd(&P.out[(size_t)(Mb * 64 + m2) * 16 + s], v);
        }
    }
}

extern "C" void kernel_launch(void* const* d_in, const int* in_sizes, int n_in,
                              void* d_out, int out_size, void* d_ws, size_t ws_size,
                              hipStream_t stream)
{
    Params P;
    P.x    = (const float*)d_in[0];
    P.bWf  = (const float*)d_in[1];
    P.bbf  = (const float*)d_in[2];
    P.bWr  = (const float*)d_in[3];
    P.bbr  = (const float*)d_in[4];
    P.tWf  = (const float*)d_in[5];
    P.tbf  = (const float*)d_in[6];
    P.tWr  = (const float*)d_in[7];
    P.tbr  = (const float*)d_in[8];
    P.donb = (const float*)d_in[9];
    P.wih0 = (const float*)d_in[10];
    P.whh0 = (const float*)d_in[11];
    P.bih0 = (const float*)d_in[12];
    P.bhh0 = (const float*)d_in[13];
    P.wih1 = (const float*)d_in[14];
    P.whh1 = (const float*)d_in[15];
    P.bih1 = (const float*)d_in[16];
    P.bhh1 = (const float*)d_in[17];
    P.pW   = (const float*)d_in[18];
    P.pb   = (const float*)d_in[19];
    P.out  = (float*)d_out;

    char* ws = (char*)d_ws;
    P.brA  = (float*)(ws);                 // 2 MB
    P.brB  = (float*)(ws + 2097152);       // 2 MB
    P.trA  = (float*)(ws + 4194304);       // 256 KB
    P.trB  = (float*)(ws + 4456448);       // 256 KB
    P.seqT = (float*)(ws + 4718592);       // 512 KB   [128][1024]
    P.h0b  = (_Float16*)(ws + 5242880);    // 1 MB
    P.h1b  = (_Float16*)(ws + 6291456);    // 1 MB
    P.mbar = (unsigned*)(ws + BAR_OFF);    // 16 counters, 128B stride
    P.gbar = (unsigned*)(ws + BAR_OFF + 2048);

    hipMemsetAsync((void*)(ws + BAR_OFF), 0, 4096, stream);   // zero barrier counters
    hipFuncSetAttribute(reinterpret_cast<const void*>(don_gru),
                        hipFuncAttributeMaxDynamicSharedMemorySize, SMEM_BYTES);
    void* args[] = { &P };
    hipLaunchCooperativeKernel(reinterpret_cast<void*>(don_gru),
                               dim3(GRID), dim3(BDIM), args, SMEM_BYTES, stream);
}

// Round 9
// 848.219 us; speedup vs baseline: 10.0238x; 1.1574x over previous
//
#include <hip/hip_runtime.h>

typedef float f32x4 __attribute__((ext_vector_type(4)));
typedef _Float16 f16x8 __attribute__((ext_vector_type(8)));
typedef unsigned long long u64;

#define BDIM 256
#define GRID 256
// LDS: wts 73728 | gates 64*149*4=38144 | misc 960 | seqL 128*64*4=32768  => 145600
#define SMEM_BYTES 145600
#define BAR_OFF 7340032u
#define AGENT __HIP_MEMORY_SCOPE_AGENT

struct Params {
    const float *x, *bWf, *bbf, *bWr, *bbr;
    const float *tWf, *tbf, *tWr, *tbr, *donb;
    const float *wih0, *whh0, *bih0, *bhh0;
    const float *wih1, *whh1, *bih1, *bhh1;
    const float *pW, *pb;
    float *out;
    float *brA, *brB, *trA, *trB, *seqT;
    _Float16 *h0b, *h1b;   // fp16 ping-pong state buffers, fragment-ready layout
    unsigned *mbar, *gbar; // barrier counters (memset to 0 before launch)
};

// ---- coherent (IF$-through, no L2 maintenance) access helpers ----
__device__ __forceinline__ void st64c(void* p, u64 v) {
    __hip_atomic_store((u64*)p, v, __ATOMIC_RELAXED, AGENT);
}
__device__ __forceinline__ u64 ld64c(const void* p) {
    return __hip_atomic_load((const u64*)p, __ATOMIC_RELAXED, AGENT);
}
__device__ __forceinline__ void st32c(float* p, float v) {
    union { float f; unsigned u; } c; c.f = v;
    __hip_atomic_store((unsigned*)p, c.u, __ATOMIC_RELAXED, AGENT);
}
__device__ __forceinline__ float ld32c(const float* p) {
    union { unsigned u; float f; } c;
    c.u = __hip_atomic_load((const unsigned*)p, __ATOMIC_RELAXED, AGENT);
    return c.f;
}
__device__ __forceinline__ float4 ld128c(const float* p) {   // 16B via 2x8B
    union { u64 q[2]; float4 v; } c;
    c.q[0] = ld64c(p); c.q[1] = ld64c(p + 2);
    return c.v;
}
// 8B coherent store on the plain-store pipe (same sc0 sc1 coherence as the
// relaxed agent atomic, but not an atomic op at the coherence point).
__device__ __forceinline__ void stc8(void* p, u64 v) {
    asm volatile("global_store_dwordx2 %0, %1, off sc0 sc1" :: "v"(p), "v"(v) : "memory");
}

__device__ __forceinline__ f16x8 cvt8(float4 a, float4 b) {
    f16x8 r;
    r[0] = (_Float16)a.x; r[1] = (_Float16)a.y; r[2] = (_Float16)a.z; r[3] = (_Float16)a.w;
    r[4] = (_Float16)b.x; r[5] = (_Float16)b.y; r[6] = (_Float16)b.z; r[7] = (_Float16)b.w;
    return r;
}

__device__ __forceinline__ unsigned short f2hbits(float x) {
    union { _Float16 h; unsigned short u; } v; v.h = (_Float16)x; return v.u;
}

__device__ __forceinline__ u64 pack4(const float* v) {
    return  (u64)f2hbits(v[0])
         | ((u64)f2hbits(v[1]) << 16)
         | ((u64)f2hbits(v[2]) << 32)
         | ((u64)f2hbits(v[3]) << 48);
}

__device__ __forceinline__ float sigmoidf_(float x) { return 1.f / (1.f + __expf(-x)); }
__device__ __forceinline__ float tanhf_(float x)    { return 1.f - 2.f / (__expf(2.f * x) + 1.f); }

// Fence-free monotonic barrier (bounded spin: broken barrier => wrong answer,
// never a hang). All cross-WG data moves via sc0/sc1 ops -> no L2 maintenance.
__device__ __forceinline__ void barwait(unsigned* c, unsigned target) {
    asm volatile("s_waitcnt vmcnt(0)" ::: "memory");   // per-wave: stores reached IF$
    __syncthreads();                                   // all waves drained
    if (threadIdx.x == 0) {
        __hip_atomic_fetch_add(c, 1u, __ATOMIC_RELAXED, AGENT);
        unsigned guard = 0;
        while (__hip_atomic_load(c, __ATOMIC_RELAXED, AGENT) < target) {
            __builtin_amdgcn_s_sleep(1);
            if (++guard > (1u << 20)) break;           // safety: never hang
        }
    }
    __syncthreads();
}

// Generic 64x64-tile GEMM: C[m0..+64, n0..+64] = op(A[M,K] @ W[N,K]^T + bias)
__device__ void gemm_tile(const float* __restrict__ A, int lda, int aCoh,
                          const float* __restrict__ W, int ldw,
                          const float* __restrict__ bias, int biasScalar,
                          int relu, float* __restrict__ C, int ldc, int transOut,
                          int K, int m0, int n0, char* smem)
{
    _Float16* At = (_Float16*)smem;            // [64][72]
    _Float16* Bt = (_Float16*)smem + 64 * 72;  // [64][72]
    const int tid = threadIdx.x;
    const int wv = tid >> 6, lane = tid & 63;
    f32x4 acc[4];
#pragma unroll
    for (int i = 0; i < 4; ++i) acc[i] = (f32x4){0.f, 0.f, 0.f, 0.f};

    const int srow = tid >> 2, sc0 = (tid & 3) * 16;
    for (int kc = 0; kc < K; kc += 64) {
        const float* asrc = A + (size_t)(m0 + srow) * lda + kc + sc0;
        const float* wsrc = W + (size_t)(n0 + srow) * ldw + kc + sc0;
#pragma unroll
        for (int h = 0; h < 2; ++h) {
            float4 v0 = make_float4(0, 0, 0, 0), v1 = v0, u0 = v0, u1 = v0;
            if (kc + sc0 + h * 8 < K) {        // K % 8 == 0 for all our shapes
                if (aCoh) {
                    v0 = ld128c(asrc + h * 8);
                    v1 = ld128c(asrc + h * 8 + 4);
                } else {
                    v0 = *(const float4*)(asrc + h * 8);
                    v1 = *(const float4*)(asrc + h * 8 + 4);
                }
                u0 = *(const float4*)(wsrc + h * 8);
                u1 = *(const float4*)(wsrc + h * 8 + 4);
            }
            *(f16x8*)&At[srow * 72 + sc0 + h * 8] = cvt8(v0, v1);
            *(f16x8*)&Bt[srow * 72 + sc0 + h * 8] = cvt8(u0, u1);
        }
        __syncthreads();
#pragma unroll
        for (int k2 = 0; k2 < 2; ++k2) {
            f16x8 a = *(const f16x8*)&At[(wv * 16 + (lane & 15)) * 72 + k2 * 32 + (lane >> 4) * 8];
#pragma unroll
            for (int nt = 0; nt < 4; ++nt) {
                f16x8 b = *(const f16x8*)&Bt[(nt * 16 + (lane & 15)) * 72 + k2 * 32 + (lane >> 4) * 8];
                acc[nt] = __builtin_amdgcn_mfma_f32_16x16x32_f16(a, b, acc[nt], 0, 0, 0);
            }
        }
        __syncthreads();
    }
#pragma unroll
    for (int nt = 0; nt < 4; ++nt) {
        const int col = n0 + nt * 16 + (lane & 15);
        const float bv = biasScalar ? bias[0] : bias[col];
#pragma unroll
        for (int i = 0; i < 4; ++i) {
            const int row = m0 + wv * 16 + (lane >> 4) * 4 + i;
            float v = acc[nt][i] + bv;
            if (relu) v = fmaxf(v, 0.f);
            if (transOut) st32c(&C[(size_t)col * ldc + row], v);
            else          st32c(&C[(size_t)row * ldc + col], v);
        }
    }
}

__global__ void __launch_bounds__(BDIM, 1) don_gru(Params P)
{
    extern __shared__ char smem[];
    const int wg = blockIdx.x, tid = threadIdx.x;
    // Group mapping (heuristic XCD-locality; correctness independent of it).
    const int xcd = wg & 7, slot = wg >> 3;
    const int Mb  = xcd + ((slot >> 4) << 3);         // 0..15
    const int hsI = slot & 15, j0 = hsI * 16;
    unsigned* mc = P.mbar + Mb * 32;                  // group counter, own 128B line
    unsigned gph = 1;

    // ---- init: zero state buffers + output via coherent stores ----
    {
        const int gid = wg * BDIM + tid;              // 65536 threads
        st64c((u64*)P.h0b + gid * 2, 0ull);
        st64c((u64*)P.h0b + gid * 2 + 1, 0ull);
        st64c((u64*)P.h1b + gid * 2, 0ull);
        st64c((u64*)P.h1b + gid * 2 + 1, 0ull);
        if (gid < 4096) {
            st64c((u64*)P.out + gid * 2, 0ull);
            st64c((u64*)P.out + gid * 2 + 1, 0ull);
        }
    }

    // ---- phase 1: branch L0 (WG 0..127) + trunk L0 elementwise (WG 128..135) ----
    if (wg < 128) {
        gemm_tile(P.x, 528, 0, P.bWf, 528, P.bbf, 0, 1, P.brA, 512, 0, 528,
                  (wg >> 3) * 64, (wg & 7) * 64, smem);
    } else if (wg < 136) {
        const int r0 = (wg - 128) * 16;
        for (int i = tid; i < 16 * 512; i += BDIM) {
            const int r = r0 + (i >> 9), o = i & 511;
            st32c(&P.trA[(size_t)r * 512 + o], fmaxf((float)r * P.tWf[o] + P.tbf[o], 0.f));
        }
    }
    barwait(P.gbar, 256u * gph); ++gph;

    // ---- phases 2..4: stacked layers ----
#pragma unroll 1
    for (int L = 0; L < 3; ++L) {
        const float* bi_ = (L & 1) ? P.brB : P.brA;
        float*       bo_ = (L & 1) ? P.brA : P.brB;
        const float* ti_ = (L & 1) ? P.trB : P.trA;
        float*       to_ = (L & 1) ? P.trA : P.trB;
        if (wg < 128)
            gemm_tile(bi_, 512, 1, P.bWr + (size_t)L * 262144, 512, P.bbr + L * 512, 0,
                      (L < 2) ? 1 : 0, bo_, 512, 0, 512, (wg >> 3) * 64, (wg & 7) * 64, smem);
        else if (wg < 144)
            gemm_tile(ti_, 512, 1, P.tWr + (size_t)L * 262144, 512, P.tbr + L * 512, 0,
                      1, to_, 512, 0, 512, ((wg - 128) >> 3) * 64, ((wg - 128) & 7) * 64, smem);
        barwait(P.gbar, 256u * gph); ++gph;
    }

    // ---- phase 5: seq^T = (branch @ trunk^T + don_bias)^T, stored [128][1024] ----
    if (wg < 32)
        gemm_tile(P.brB, 512, 1, P.trB, 512, P.donb, 1, 0, P.seqT, 1024, 1, 512,
                  (wg >> 1) * 64, (wg & 1) * 64, smem);
    barwait(P.gbar, 256u * gph); ++gph;

    // ---- phase 6: stage weights + seq slice into LDS (per-WG) ----
    _Float16* wts  = (_Float16*)smem;                 // [144][256] swizzled
    float* gates = (float*)(smem + 73728);            // [64][149]
    float* misc  = (float*)(smem + 111872);           // bh0|wi0|bi0|bi1|bh1, 48 each
    float* seqL  = (float*)(smem + 112832);           // [128][64]
    {
#pragma unroll 1
        for (int rep = 0; rep < 9; ++rep) {
            const int r = rep * 16 + (tid >> 4);      // 0..143
            const int mat = r / 48, rem = r % 48;
            const int u = rem / 3, g = rem % 3;
            const int grow = g * 256 + j0 + u;
            const float* src = (mat == 0 ? P.whh0 : (mat == 1 ? P.wih1 : P.whh1))
                               + (size_t)grow * 256 + (tid & 15) * 16;
#pragma unroll
            for (int h = 0; h < 2; ++h) {
                float4 a = *(const float4*)(src + h * 8);
                float4 b = *(const float4*)(src + h * 8 + 4);
                const int q = ((tid & 15) * 2 + h) ^ (r & 7);
                *(f16x8*)&wts[r * 256 + q * 8] = cvt8(a, b);
            }
        }
        for (int i = tid; i < 128 * 64; i += BDIM)    // seq slice: 32KB, coalesced
            seqL[i] = ld32c(P.seqT + (size_t)(i >> 6) * 1024 + Mb * 64 + (i & 63));
        if (tid < 48) {
            const int u = tid / 3, g = tid % 3;
            const int grow = g * 256 + j0 + u;
            misc[tid]       = P.bhh0[grow];
            misc[48 + tid]  = P.wih0[grow];   // [768][1] flat
            misc[96 + tid]  = P.bih0[grow];
            misc[144 + tid] = P.bih1[grow];
            misc[192 + tid] = P.bhh1[grow];
        }
    }
    __syncthreads();

    // ---- phases 7..135: recurrence, layer1 pipelined one step behind layer0 ----
    float h0f[4] = {0, 0, 0, 0}, h1f[4] = {0, 0, 0, 0};
    const int wv = tid >> 6, lane = tid & 63;
    const int am = wv * 16 + (lane & 15);
    const int m = lane, jq = wv;

#pragma unroll 1
    for (int p = 0; p <= 128; ++p) {
        const int rb = p & 1;
        const _Float16* h0r = P.h0b + rb * 262144 + Mb * 16384;
        const _Float16* h1r = P.h1b + rb * 262144 + Mb * 16384;

        // Issue all 16 A-fragment loads as 16B sc0/sc1 coherent loads (plain
        // load pipe, not atomics), then wait once. sched_barrier pins the
        // MFMA block below the waitcnt (rule #18).
        f16x8 a0v[8], a1v[8];
#pragma unroll
        for (int ks = 0; ks < 8; ++ks) {
            const int kc = ks * 4 + (lane >> 4);
            const _Float16* p0 = h0r + (kc * 64 + am) * 8;
            const _Float16* p1 = h1r + (kc * 64 + am) * 8;
            asm volatile("global_load_dwordx4 %0, %1, off sc0 sc1"
                         : "=v"(a0v[ks]) : "v"(p0));
            asm volatile("global_load_dwordx4 %0, %1, off sc0 sc1"
                         : "=v"(a1v[ks]) : "v"(p1));
        }
        asm volatile("s_waitcnt vmcnt(0)" ::: "memory");
        __builtin_amdgcn_sched_barrier(0);

        f32x4 acc[9];
#pragma unroll
        for (int i = 0; i < 9; ++i) acc[i] = (f32x4){0.f, 0.f, 0.f, 0.f};
#pragma unroll
        for (int ks = 0; ks < 8; ++ks) {
#pragma unroll
            for (int nt = 0; nt < 9; ++nt) {   // 0..5: A=h0 (gh0,gi1), 6..8: A=h1 (gh1)
                const int rr = nt * 16 + (lane & 15);
                const int q = (ks * 4 + (lane >> 4)) ^ (rr & 7);
                const f16x8 b = *(const f16x8*)&wts[rr * 256 + q * 8];
                acc[nt] = __builtin_amdgcn_mfma_f32_16x16x32_f16(nt < 6 ? a0v[ks] : a1v[ks],
                                                                 b, acc[nt], 0, 0, 0);
            }
        }
#pragma unroll
        for (int nt = 0; nt < 9; ++nt) {
            const int gn = nt * 16 + (lane & 15);
#pragma unroll
            for (int i = 0; i < 4; ++i)
                gates[(wv * 16 + (lane >> 4) * 4 + i) * 149 + gn] = acc[nt][i];
        }
        __syncthreads();

        const int wb = rb ^ 1;
        if (p < 128) {      // layer0 step p
            const float xin = seqL[p * 64 + m];
#pragma unroll
            for (int i = 0; i < 4; ++i) {
                const int n3 = 3 * (jq * 4 + i);
                const float gr  = gates[m * 149 + n3 + 0] + misc[n3 + 0];
                const float gz  = gates[m * 149 + n3 + 1] + misc[n3 + 1];
                const float gnn = gates[m * 149 + n3 + 2] + misc[n3 + 2];
                const float ir  = xin * misc[48 + n3 + 0] + misc[96 + n3 + 0];
                const float iz  = xin * misc[48 + n3 + 1] + misc[96 + n3 + 1];
                const float inn = xin * misc[48 + n3 + 2] + misc[96 + n3 + 2];
                const float r_ = sigmoidf_(ir + gr);
                const float z_ = sigmoidf_(iz + gz);
                const float nn = tanhf_(inn + r_ * gnn);
                h0f[i] = (1.f - z_) * nn + z_ * h0f[i];
            }
            stc8(P.h0b + wb * 262144 + Mb * 16384
                 + ((hsI * 2 + (jq >> 1)) * 64 + m) * 8 + (jq & 1) * 4, pack4(h0f));
        }
        if (p >= 1) {       // layer1 step p-1
#pragma unroll
            for (int i = 0; i < 4; ++i) {
                const int n3 = 3 * (jq * 4 + i);
                const float ir  = gates[m * 149 + 48 + n3 + 0] + misc[144 + n3 + 0];
                const float iz  = gates[m * 149 + 48 + n3 + 1] + misc[144 + n3 + 1];
                const float inn = gates[m * 149 + 48 + n3 + 2] + misc[144 + n3 + 2];
                const float hr  = gates[m * 149 + 96 + n3 + 0] + misc[192 + n3 + 0];
                const float hz  = gates[m * 149 + 96 + n3 + 1] + misc[192 + n3 + 1];
                const float hn  = gates[m * 149 + 96 + n3 + 2] + misc[192 + n3 + 2];
                const float r_ = sigmoidf_(ir + hr);
                const float z_ = sigmoidf_(iz + hz);
                const float nn = tanhf_(inn + r_ * hn);
                h1f[i] = (1.f - z_) * nn + z_ * h1f[i];
            }
            stc8(P.h1b + wb * 262144 + Mb * 16384
                 + ((hsI * 2 + (jq >> 1)) * 64 + m) * 8 + (jq & 1) * 4, pack4(h1f));
        }
        barwait(mc, 16u * (unsigned)(p + 1));   // 16-WG group barrier (fence-free)
    }

    // ---- projection: out = h1 @ pW^T + pb (partial per CU, atomicAdd reduce) ----
    {
        float ps[16];
#pragma unroll
        for (int s = 0; s < 16; ++s) {
            float v = 0.f;
#pragma unroll
            for (int i = 0; i < 4; ++i)
                v += h1f[i] * P.pW[s * 256 + j0 + jq * 4 + i];
            ps[s] = v;
        }
        float* proj = gates;                 // reuse: [4][64][16]
#pragma unroll
        for (int s = 0; s < 16; ++s) proj[(jq * 64 + m) * 16 + s] = ps[s];
        __syncthreads();
        const int m2 = tid >> 2, s0 = (tid & 3) * 4;
#pragma unroll
        for (int si = 0; si < 4; ++si) {
            const int s = s0 + si;
            float v = proj[(0 * 64 + m2) * 16 + s] + proj[(1 * 64 + m2) * 16 + s]
                    + proj[(2 * 64 + m2) * 16 + s] + proj[(3 * 64 + m2) * 16 + s];
            if (hsI == 0) v += P.pb[s];
            atomicAdd(&P.out[(size_t)(Mb * 64 + m2) * 16 + s], v);
        }
    }
}

extern "C" void kernel_launch(void* const* d_in, const int* in_sizes, int n_in,
                              void* d_out, int out_size, void* d_ws, size_t ws_size,
                              hipStream_t stream)
{
    Params P;
    P.x    = (const float*)d_in[0];
    P.bWf  = (const float*)d_in[1];
    P.bbf  = (const float*)d_in[2];
    P.bWr  = (const float*)d_in[3];
    P.bbr  = (const float*)d_in[4];
    P.tWf  = (const float*)d_in[5];
    P.tbf  = (const float*)d_in[6];
    P.tWr  = (const float*)d_in[7];
    P.tbr  = (const float*)d_in[8];
    P.donb = (const float*)d_in[9];
    P.wih0 = (const float*)d_in[10];
    P.whh0 = (const float*)d_in[11];
    P.bih0 = (const float*)d_in[12];
    P.bhh0 = (const float*)d_in[13];
    P.wih1 = (const float*)d_in[14];
    P.whh1 = (const float*)d_in[15];
    P.bih1 = (const float*)d_in[16];
    P.bhh1 = (const float*)d_in[17];
    P.pW   = (const float*)d_in[18];
    P.pb   = (const float*)d_in[19];
    P.out  = (float*)d_out;

    char* ws = (char*)d_ws;
    P.brA  = (float*)(ws);                 // 2 MB
    P.brB  = (float*)(ws + 2097152);       // 2 MB
    P.trA  = (float*)(ws + 4194304);       // 256 KB
    P.trB  = (float*)(ws + 4456448);       // 256 KB
    P.seqT = (float*)(ws + 4718592);       // 512 KB   [128][1024]
    P.h0b  = (_Float16*)(ws + 5242880);    // 1 MB
    P.h1b  = (_Float16*)(ws + 6291456);    // 1 MB
    P.mbar = (unsigned*)(ws + BAR_OFF);    // 16 counters, 128B stride
    P.gbar = (unsigned*)(ws + BAR_OFF + 2048);

    hipMemsetAsync((void*)(ws + BAR_OFF), 0, 4096, stream);   // zero barrier counters
    hipFuncSetAttribute(reinterpret_cast<const void*>(don_gru),
                        hipFuncAttributeMaxDynamicSharedMemorySize, SMEM_BYTES);
    void* args[] = { &P };
    hipLaunchCooperativeKernel(reinterpret_cast<void*>(don_gru),
                               dim3(GRID), dim3(BDIM), args, SMEM_BYTES, stream);
}